// Round 10
// baseline (162.425 us; speedup 1.0000x reference)
//
#include <hip/hip_runtime.h>

// WL_DiffNet bf16-MFMA, round 10 (mega6): scalar-addressed, software-pipelined
// gather + 2-deep B prefetch.
//   - gather: pk values are wave-uniform -> readfirstlane -> SALU addressing;
//     2-row register double-buffer (static indices) hides L2/L3 latency.
//   - B: fragment-major packed W, named bE/bO pairs prefetched 2 kt ahead,
//     kt-loops unrolled x2 and split at the A_/N_ switch (all static).
//   - structure/LDS/swizzles identical to round 9 (absmax must stay 0.0625).

#define BB 64
#define NN 512
#define MAXNB 10
#define HH 256
#define ROWS (BB*NN)   // 32768
#define BM 64          // rows per block
#define ZROW 32768     // zero row index in G/Hb2 buffers

typedef __attribute__((ext_vector_type(8))) short bf16x8;
typedef __attribute__((ext_vector_type(4))) float f32x4;
typedef unsigned short u16;
typedef unsigned int u32;
typedef __attribute__((address_space(3))) u32 lds_u32;
typedef __attribute__((address_space(1))) const u32 glb_u32;

__device__ __forceinline__ u16 f2b(float f) {   // rne f32->bf16
    union { float f; u32 u; } v; v.f = f;
    u32 r = v.u + 0x7FFF + ((v.u >> 16) & 1);
    return (u16)(r >> 16);
}
__device__ __forceinline__ float b2f(u32 u) {   // low 16 bits -> f32
    union { u32 u; float f; } v; v.u = u << 16; return v.f;
}
__device__ __forceinline__ float b2fh(u32 u) {  // high 16 bits -> f32
    union { u32 u; float f; } v; v.u = u & 0xffff0000u; return v.f;
}
__device__ __forceinline__ void gl16(const u16* g, u16* l) {
    __builtin_amdgcn_global_load_lds((glb_u32*)g, (lds_u32*)l, 16, 0, 0);
}
// XCD-bijective swizzle (nwg % 8 == 0)
__device__ __forceinline__ int xcd_swz(int bid, int nwg) {
    return (bid & 7) * (nwg >> 3) + (bid >> 3);
}

// ---- one-time prep -------------------------------------------------------

__global__ __launch_bounds__(256) void castk(const float* __restrict__ in,
                                             u16* __restrict__ out) {
    int i = blockIdx.x * 256 + threadIdx.x;
    float4 v = ((const float4*)in)[i];
    u32 a = f2b(v.x) | ((u32)f2b(v.y) << 16);
    u32 b = f2b(v.z) | ((u32)f2b(v.w) << 16);
    ((uint2*)out)[i] = make_uint2(a, b);
}

__global__ __launch_bounds__(256) void hb2_kernel(const float* __restrict__ bond,
                                                  const float* __restrict__ W2,
                                                  const float* __restrict__ b2,
                                                  u16* __restrict__ Hb2) {
    int c = threadIdx.x;
    int r0 = blockIdx.x * 8;
    float w[5];
#pragma unroll
    for (int f = 0; f < 5; ++f) w[f] = W2[(size_t)(HH + f) * HH + c];
    float bb = b2[c];
    for (int r = r0; r < r0 + 8; ++r) {
        float s = bb;
#pragma unroll
        for (int f = 0; f < 5; ++f) s += bond[r * 5 + f] * w[f];
        Hb2[(size_t)r * HH + c] = f2b(s);
    }
}

// pk[t] = absrowA | absrowB<<16; invalid -> ZROW (zeroed row)
__global__ __launch_bounds__(256) void pkk(const int* __restrict__ agr,
                                           const int* __restrict__ bgr,
                                           const int* __restrict__ nnb,
                                           u32* __restrict__ pk) {
    int t = blockIdx.x * 256 + threadIdx.x;   // < 327680
    int r = t / 10, k = t - r * 10;
    int brow = (r >> 9) << 9;
    bool valid = (k < nnb[r]);
    u32 pA = valid ? (u32)(brow + agr[t * 2 + 1]) : (u32)ZROW;
    u32 pB = valid ? (u32)(brow + bgr[t * 2 + 1]) : (u32)ZROW;
    pk[t] = pA | (pB << 16);
}

// fragment-major weight pack: Wp[((kt*16+nq)*64+lane)*8 + e] =
//   bf16(W[(kt*32 + (lane>>4)*8 + e) * 256 + nq*16 + (lane&15)])
__global__ __launch_bounds__(256) void wpk(const float* __restrict__ W,
                                           u16* __restrict__ Wp) {
    int o = blockIdx.x * 256 + threadIdx.x;
    int e = o & 7, lane = (o >> 3) & 63, nq = (o >> 9) & 15, kt = o >> 13;
    int k = kt * 32 + (lane >> 4) * 8 + e;
    int n = nq * 16 + (lane & 15);
    Wp[o] = f2b(W[(size_t)k * HH + n]);
}

// zero row ZROW of G0/G1/Hb2
__global__ __launch_bounds__(256) void zrow(u16* G0, u16* G1, u16* Hb2) {
    int t = threadIdx.x;
    G0[(size_t)ZROW * 256 + t] = 0;
    G1[(size_t)ZROW * 256 + t] = 0;
    Hb2[(size_t)ZROW * 256 + t] = 0;
}

// ---- mega6 ---------------------------------------------------------------
// 512 thr, 8 waves; wave wc owns cols wc*32..+32, all 64 rows.
// LDS 64KB: A_ (F -> F') + N_ (N -> G'). B direct from packed W.

__global__ __launch_bounds__(512, 4) void mega6(const u16* __restrict__ Fbf,
                                                const u16* __restrict__ Gall,
                                                const u16* __restrict__ Hall,
                                                const u32* __restrict__ pk,
                                                const u16* __restrict__ Wp1,
                                                const float* __restrict__ b1,
                                                const u16* __restrict__ Wp2,
                                                u16* __restrict__ Fout,
                                                u16* __restrict__ Gout) {
    __shared__ u16 A_[BM * 256];   // 32KB
    __shared__ u16 N_[BM * 256];   // 32KB

    int tid = threadIdx.x;
    int base = xcd_swz(blockIdx.x, gridDim.x) * BM;
    int lane = tid & 63, wid = tid >> 6;
    int wc = wid, m = lane & 15, g = lane >> 4;

    // stage F -> A_ (async)
#pragma unroll
    for (int q = 0; q < 4; ++q) {
        int c = (wid * 4 + q) * 64 + lane;
        int r = c >> 5, ph = c & 31;
        gl16(Fbf + (size_t)(base + r) * 256 + (ph ^ (r & 7)) * 8,
             A_ + (wid * 4 + q) * 512);
    }

    auto ldw = [&](const u16* Wp, int kt, int j) {
        return *(const uint4*)(Wp + ((size_t)(kt * 16 + wc * 2 + j) * 64 + lane) * 8);
    };
    auto step = [&](const u16* Ar, int kt, f32x4 (&ac)[4][2],
                    const uint4& b0, const uint4& b1) {
        int asl = (kt & 7) * 4 + g;
        bf16x8 bb0 = *(const bf16x8*)&b0, bb1 = *(const bf16x8*)&b1;
#pragma unroll
        for (int mi = 0; mi < 4; ++mi) {
            int r = mi * 16 + m;
            bf16x8 af = *(const bf16x8*)(Ar + r * 256 + ((asl ^ (r & 7)) * 8));
            ac[mi][0] = __builtin_amdgcn_mfma_f32_16x16x32_bf16(af, bb0, ac[mi][0], 0, 0, 0);
            ac[mi][1] = __builtin_amdgcn_mfma_f32_16x16x32_bf16(af, bb1, ac[mi][1], 0, 0, 0);
        }
    };

    // B preload kt0,kt1 (before gather: ~3000cy of cover before first use)
    const u16* Wp0 = Wp1 ? Wp1 : Wp2;
    uint4 bE0 = ldw(Wp0, 0, 0), bE1 = ldw(Wp0, 0, 1);
    uint4 bO0 = ldw(Wp0, 1, 0), bO1 = ldw(Wp0, 1, 1);

    if (Wp1) {
        // ---- gather: scalar-addressed, 2-row software pipeline ----
        const uint2* Gb = (const uint2*)Gall;
        const uint2* Hb = (const uint2*)Hall;
        const u32* pkr = pk + ((size_t)base + wid * 8) * 10;

        auto gissue = [&](int i, uint2 (&gb)[10], uint2 (&hb)[10]) {
#pragma unroll
            for (int k = 0; k < 10; ++k) {
                u32 p = (u32)__builtin_amdgcn_readfirstlane((int)pkr[i * 10 + k]);
                gb[k] = Gb[(size_t)(p & 0xffffu) * 64 + lane];
                hb[k] = Hb[(size_t)(p >> 16) * 64 + lane];
            }
        };
        auto gsum = [&](int i, const uint2 (&gb)[10], const uint2 (&hb)[10]) {
            float s0 = 0.f, s1 = 0.f, s2 = 0.f, s3 = 0.f;
#pragma unroll
            for (int k = 0; k < 10; ++k) {
                s0 += fmaxf(b2f(gb[k].x) + b2f(hb[k].x), 0.f);
                s1 += fmaxf(b2fh(gb[k].x) + b2fh(hb[k].x), 0.f);
                s2 += fmaxf(b2f(gb[k].y) + b2f(hb[k].y), 0.f);
                s3 += fmaxf(b2fh(gb[k].y) + b2fh(hb[k].y), 0.f);
            }
            int r = wid * 8 + i;
            u32 lo = f2b(s0) | ((u32)f2b(s1) << 16);
            u32 hi = f2b(s2) | ((u32)f2b(s3) << 16);
            int s16 = (lane >> 1) ^ (r & 7);
            *(uint2*)(N_ + r * 256 + s16 * 8 + (lane & 1) * 4) = make_uint2(lo, hi);
        };

        uint2 gA[10], hA[10], gB[10], hB[10];
        gissue(0, gA, hA);
#pragma unroll
        for (int i = 0; i < 8; i += 2) {
            gissue(i + 1, gB, hB);
            gsum(i, gA, hA);
            if (i + 2 < 8) gissue(i + 2, gA, hA);
            gsum(i + 1, gB, hB);
        }
        __syncthreads();   // B1: A_ staged + N_ written

        f32x4 acc[4][2];
#pragma unroll
        for (int mi = 0; mi < 4; ++mi)
#pragma unroll
            for (int j = 0; j < 2; ++j) acc[mi][j] = (f32x4){0.f, 0.f, 0.f, 0.f};

        // phase-1a: kt 0..7 from A_ (2-deep B prefetch)
#pragma unroll
        for (int kt = 0; kt < 8; kt += 2) {
            step(A_, kt, acc, bE0, bE1);
            bE0 = ldw(Wp1, kt + 2, 0); bE1 = ldw(Wp1, kt + 2, 1);
            step(A_, kt + 1, acc, bO0, bO1);
            bO0 = ldw(Wp1, kt + 3, 0); bO1 = ldw(Wp1, kt + 3, 1);
        }
        // phase-1b: kt 8..15 from N_
#pragma unroll
        for (int kt = 8; kt < 16; kt += 2) {
            step(N_, kt, acc, bE0, bE1);
            if (kt + 2 < 16)      { bE0 = ldw(Wp1, kt + 2, 0); bE1 = ldw(Wp1, kt + 2, 1); }
            else if (Gout)        { bE0 = ldw(Wp2, 0, 0);      bE1 = ldw(Wp2, 0, 1); }
            step(N_, kt + 1, acc, bO0, bO1);
            if (kt + 3 < 16)      { bO0 = ldw(Wp1, kt + 3, 0); bO1 = ldw(Wp1, kt + 3, 1); }
            else if (Gout)        { bO0 = ldw(Wp2, 1, 0);      bO1 = ldw(Wp2, 1, 1); }
        }
        __syncthreads();   // B2: all waves done reading A_/N_

        // F' = relu(acc+b1) -> A_
#pragma unroll
        for (int mi = 0; mi < 4; ++mi)
#pragma unroll
            for (int j = 0; j < 2; ++j) {
                int col = wc * 32 + j * 16 + m;
                float bb = b1[col];
#pragma unroll
                for (int rr = 0; rr < 4; ++rr) {
                    int r = mi * 16 + g * 4 + rr;
                    A_[r * 256 + ((col >> 3) ^ (r & 7)) * 8 + (col & 7)] =
                        f2b(fmaxf(acc[mi][j][rr] + bb, 0.f));
                }
            }
        __syncthreads();   // B3: F' visible

        // coalesced F' store
#pragma unroll
        for (int i = 0; i < 4; ++i) {
            int c = tid + i * 512;
            int r = c >> 5, ph = c & 31;
            uint4 v = ((const uint4*)A_)[r * 32 + ph];
            ((uint4*)(Fout + (size_t)(base + r) * 256))[ph ^ (r & 7)] = v;
        }
    } else {
        __syncthreads();   // B1: A_ staged (skip-mode)
    }

    if (!Gout) return;

    // phase-2: G' = A_(F') @ W2a, K=256 (bE/bO hold Wp2 kt0,kt1)
    f32x4 gacc[4][2];
#pragma unroll
    for (int mi = 0; mi < 4; ++mi)
#pragma unroll
        for (int j = 0; j < 2; ++j) gacc[mi][j] = (f32x4){0.f, 0.f, 0.f, 0.f};

#pragma unroll
    for (int kt = 0; kt < 8; kt += 2) {
        step(A_, kt, gacc, bE0, bE1);
        if (kt + 2 < 8) { bE0 = ldw(Wp2, kt + 2, 0); bE1 = ldw(Wp2, kt + 2, 1); }
        step(A_, kt + 1, gacc, bO0, bO1);
        if (kt + 3 < 8) { bO0 = ldw(Wp2, kt + 3, 0); bO1 = ldw(Wp2, kt + 3, 1); }
    }

    // G' -> N_ bounce, then coalesced store
#pragma unroll
    for (int mi = 0; mi < 4; ++mi)
#pragma unroll
        for (int j = 0; j < 2; ++j) {
            int col = wc * 32 + j * 16 + m;
#pragma unroll
            for (int rr = 0; rr < 4; ++rr) {
                int r = mi * 16 + g * 4 + rr;
                N_[r * 256 + ((col >> 3) ^ (r & 7)) * 8 + (col & 7)] =
                    f2b(gacc[mi][j][rr]);
            }
        }
    __syncthreads();   // B4: G' visible
#pragma unroll
    for (int i = 0; i < 4; ++i) {
        int c = tid + i * 512;
        int r = c >> 5, ph = c & 31;
        uint4 v = ((const uint4*)N_)[r * 32 + ph];
        ((uint4*)(Gout + (size_t)(base + r) * 256))[ph ^ (r & 7)] = v;
    }
}

// ---- final sum over atoms (deterministic) --------------------------------

__global__ __launch_bounds__(256) void sum_bf16(const u16* __restrict__ F,
                                                float* __restrict__ out) {
    __shared__ float red[4][256];
    int b = blockIdx.x, tid = threadIdx.x;
    int cg = tid & 63, rg = tid >> 6;
    float s0 = 0, s1 = 0, s2 = 0, s3 = 0;
    const u16* Fb = F + (size_t)(b * NN + rg * 128) * 256 + cg * 4;
    for (int n = 0; n < 128; ++n) {
        ushort4 v = *(const ushort4*)(Fb + (size_t)n * 256);
        s0 += b2f(v.x); s1 += b2f(v.y); s2 += b2f(v.z); s3 += b2f(v.w);
    }
    red[rg][cg * 4 + 0] = s0; red[rg][cg * 4 + 1] = s1;
    red[rg][cg * 4 + 2] = s2; red[rg][cg * 4 + 3] = s3;
    __syncthreads();
    if (rg == 0) {
#pragma unroll
        for (int j = 0; j < 4; ++j) {
            int cc = cg * 4 + j;
            out[b * 256 + cc] = (red[0][cc] + red[1][cc]) + (red[2][cc] + red[3][cc]);
        }
    }
}

extern "C" void kernel_launch(void* const* d_in, const int* in_sizes, int n_in,
                              void* d_out, int out_size, void* d_ws, size_t ws_size,
                              hipStream_t stream) {
    const float* input_bond    = (const float*)d_in[1];
    const int*   atom_graph    = (const int*)d_in[2];
    const int*   bond_graph    = (const int*)d_in[3];
    const int*   num_nbs       = (const int*)d_in[4];
    const float* atom_features = (const float*)d_in[5];
    const float* W2 = (const float*)d_in[6];
    const float* b2 = (const float*)d_in[7];
    const float* W1 = (const float*)d_in[8];
    const float* b1 = (const float*)d_in[9];
    float* out = (float*)d_out;

    char* w = (char*)d_ws;
    u16* f0  = (u16*)w;                          // 16MB
    u16* f1  = (u16*)(w + ((size_t)16 << 20));   // 16MB
    u16* G0  = (u16*)(w + ((size_t)32 << 20));   // 16MB + zero row
    u16* G1  = (u16*)(w + ((size_t)49 << 20));   // 16MB + zero row
    u16* Hb2 = (u16*)(w + ((size_t)66 << 20));   // 16MB + zero row
    u16* Wp1 = (u16*)(w + ((size_t)83 << 20));            // 256KB
    u16* Wp2 = (u16*)(w + ((size_t)83 << 20) + (512 << 10)); // 128KB
    u32* pk  = (u32*)(w + ((size_t)84 << 20));   // 1.25MB

    castk<<<ROWS * HH / 1024, 256, 0, stream>>>(atom_features, f0);
    hb2_kernel<<<ROWS / 8, 256, 0, stream>>>(input_bond, W2, b2, Hb2);
    pkk<<<ROWS * MAXNB / 256, 256, 0, stream>>>(atom_graph, bond_graph, num_nbs, pk);
    wpk<<<512, 256, 0, stream>>>(W1, Wp1);   // kt 0..15
    wpk<<<256, 256, 0, stream>>>(W2, Wp2);   // kt 0..7 (W2a part)
    zrow<<<1, 256, 0, stream>>>(G0, G1, Hb2);

    // G0 = F0 @ W2a  (skip-mode)
    mega6<<<ROWS / BM, 512, 0, stream>>>(f0, nullptr, nullptr, nullptr,
                                         nullptr, nullptr, Wp2, nullptr, G0);
    // depth 0..2 (G ping-pong; last depth skips phase-2)
    mega6<<<ROWS / BM, 512, 0, stream>>>(f0, G0, Hb2, pk, Wp1, b1, Wp2, f1, G1);
    mega6<<<ROWS / BM, 512, 0, stream>>>(f1, G1, Hb2, pk, Wp1, b1, Wp2, f0, G0);
    mega6<<<ROWS / BM, 512, 0, stream>>>(f0, G0, Hb2, pk, Wp1, b1, Wp2, f1, nullptr);

    sum_bf16<<<BB, 256, 0, stream>>>(f1, out);
}